// Round 7
// baseline (106.580 us; speedup 1.0000x reference)
//
#include <hip/hip_runtime.h>
#include <math.h>

#define TAU_INV (1.0f / 0.07f)
#define KSEL 50
#define KPAD 64      // zero-padded rows 50..63: dot=0 -> exp=1 -> subtract 14
#define NPIX 8192
#define CCH 128
#define HWSZ 4096
#define NCLS 4
#define EPSL 1e-8f
#define NBINS 1026
#define PXT 32       // pixels per loss block
#define SROW 132     // LDS row stride in floats

// ---------------------------------------------------------------------------
// Kernel 1 (prep, 260 blocks x 1024 threads):
//   blocks 0..3   : per-class top-50, 1024 threads (r5/r6 logic verbatim).
//   blocks 4..259 : L2-normalize+transpose input/positive with ALL 1024
//                   threads per 64-pixel tile (r6 used only 256 of 1024 ->
//                   half the CU's active waves; this restores full TLP).
// ---------------------------------------------------------------------------
__global__ void __launch_bounds__(1024) prep_kernel(
        const float* __restrict__ input, const float* __restrict__ positive,
        const float* __restrict__ negative,
        const float* __restrict__ ilog, const float* __restrict__ nlog,
        float* __restrict__ ni, float* __restrict__ np_,
        float* __restrict__ nnsel,
        int* __restrict__ perm, int* __restrict__ cnt,
        float* __restrict__ out) {
    __shared__ union {
        struct {                       // norm+transpose path (~37.6 KB)
            float tile[CCH][65];
            float partial[16][64];
            float invn[64];
        } a;
        struct {                       // topk path (~21.2 KB)
            unsigned hist[NBINS];
            unsigned coarse[33];
            unsigned long long cand[2048];
            unsigned wsum[16];
            int topk_l[KPAD];
            unsigned above_cnt, cand_cnt;
            int sB, sc0;
        } b;
    } sm;

    int t = threadIdx.x;
    int bid = blockIdx.x;

    if (bid >= NCLS) {
        // ---- norm+transpose: input (blk 0..127), positive (128..255) ----
        int blk = bid - NCLS;
        int tensor = blk >> 7, chunk = blk & 127;
        const float* src = (tensor == 0) ? input : positive;
        float*       dst = (tensor == 0) ? ni    : np_;

        int n0 = chunk * 64;
        int b = n0 >> 12, hw0 = n0 & (HWSZ - 1);
        const float* base = src + (size_t)b * CCH * HWSZ + hw0;

        // load: 2048 float4 over 1024 threads (2 each); conflict-free LDS
        #pragma unroll
        for (int i = 0; i < 2; ++i) {
            int lin = t + i * 1024;
            int cc = lin >> 4, hwq = (lin & 15) * 4;
            float4 v = *(const float4*)&base[(size_t)cc * HWSZ + hwq];
            sm.a.tile[cc][hwq + 0] = v.x; sm.a.tile[cc][hwq + 1] = v.y;
            sm.a.tile[cc][hwq + 2] = v.z; sm.a.tile[cc][hwq + 3] = v.w;
        }
        __syncthreads();

        // sumsq: 16 parts x 8 channels each, per pixel column
        {
            int nof = t & 63, part = t >> 6;
            float s = 0.f;
            #pragma unroll
            for (int j = 0; j < 8; ++j) {
                float v = sm.a.tile[part * 8 + j][nof];
                s += v * v;
            }
            sm.a.partial[part][nof] = s;
        }
        __syncthreads();
        if (t < 64) {
            float tot = 0.f;
            #pragma unroll
            for (int p = 0; p < 16; ++p) tot += sm.a.partial[p][t];
            sm.a.invn[t] = 1.0f / fmaxf(sqrtf(tot), 1e-12f);
        }
        __syncthreads();

        // store: gather 4 consecutive channels -> one float4 store (2/thread)
        #pragma unroll
        for (int i = 0; i < 2; ++i) {
            int lin = t + i * 1024;
            int nf = lin >> 5, cq = (lin & 31) * 4;
            float inv = sm.a.invn[nf];
            float4 o;
            o.x = sm.a.tile[cq + 0][nf] * inv;
            o.y = sm.a.tile[cq + 1][nf] * inv;
            o.z = sm.a.tile[cq + 2][nf] * inv;
            o.w = sm.a.tile[cq + 3][nf] * inv;
            *(float4*)&dst[(size_t)(n0 + nf) * CCH + cq] = o;
        }
        return;
    }

    // ---- topk path (r5/r6 verbatim): class c, 1024 threads, 8 px/thread ----
    int c = bid;
    if (c == 0 && t == 0) out[0] = 0.0f;

    for (int i = t; i < NBINS; i += 1024) sm.b.hist[i] = 0;
    if (t < 33) sm.b.coarse[t] = 0;
    if (t == 0) { sm.b.above_cnt = 0; sm.b.cand_cnt = 0; }
    __syncthreads();

    // Phase 1: inline seg -> histogram + same-class membership bitmask.
    unsigned keys[8];
    unsigned mask = 0u;
    #pragma unroll
    for (int s = 0; s < 2; ++s) {
        int i4 = (t * 2 + s) * 4;
        int b = i4 >> 12, hw = i4 & (HWSZ - 1);

        const float* pi = ilog + (size_t)b * NCLS * HWSZ + hw;
        float4 a0 = *(const float4*)&pi[0];
        float4 a1 = *(const float4*)&pi[HWSZ];
        float4 a2 = *(const float4*)&pi[2 * HWSZ];
        float4 a3 = *(const float4*)&pi[3 * HWSZ];
        const float* pn = nlog + (size_t)b * NCLS * HWSZ + hw;
        float4 b0 = *(const float4*)&pn[0];
        float4 b1 = *(const float4*)&pn[HWSZ];
        float4 b2 = *(const float4*)&pn[2 * HWSZ];
        float4 b3 = *(const float4*)&pn[3 * HWSZ];

        const float* A0 = (const float*)&a0; const float* A1 = (const float*)&a1;
        const float* A2 = (const float*)&a2; const float* A3 = (const float*)&a3;
        const float* B0 = (const float*)&b0; const float* B1 = (const float*)&b1;
        const float* B2 = (const float*)&b2; const float* B3 = (const float*)&b3;
        #pragma unroll
        for (int j = 0; j < 4; ++j) {
            float l0 = A0[j], l1 = A1[j], l2 = A2[j], l3 = A3[j];
            int bi = 0; float bv = l0;
            if (l1 > bv) { bv = l1; bi = 1; }
            if (l2 > bv) { bv = l2; bi = 2; }
            if (l3 > bv) { bv = l3; bi = 3; }
            if (bi == c) mask |= (1u << (s * 4 + j));

            float m0 = B0[j], m1 = B1[j], m2 = B2[j], m3 = B3[j];
            int ci = 0; float cv = m0;
            if (m1 > cv) { cv = m1; ci = 1; }
            if (m2 > cv) { cv = m2; ci = 2; }
            if (m3 > cv) { cv = m3; ci = 3; }
            float ssum = expf(m0 - cv) + expf(m1 - cv) + expf(m2 - cv) + expf(m3 - cv);
            float npv = 1.0f / ssum;

            float v = (ci != c) ? npv : 0.0f;
            unsigned key = __float_as_uint(v);
            keys[s * 4 + j] = key;
            int bin = (key < 0x3E800000u) ? 0 : (int)(1u + ((key - 0x3E800000u) >> 14));
            atomicAdd(&sm.b.hist[bin], 1u);
        }
    }

    // Phase 1b: atomic-free bucketing via wave scan; ascending pixel order.
    {
        int cnt_t = __popc(mask);
        int lane = t & 63, wv = t >> 6;
        int x = cnt_t;
        #pragma unroll
        for (int off = 1; off < 64; off <<= 1) {
            int o = __shfl_up(x, off);
            if (lane >= off) x += o;
        }
        if (lane == 63) sm.b.wsum[wv] = (unsigned)x;
        __syncthreads();                 // wsum ready; hist atomics also done
        int base = x - cnt_t;
        for (int ww = 0; ww < wv; ++ww) base += (int)sm.b.wsum[ww];
        unsigned mm = mask;
        while (mm) {
            int bit = __ffs(mm) - 1; mm &= (mm - 1);
            perm[c * NPIX + base] = t * 8 + bit;   // px = 8t + bit
            ++base;
        }
        if (t == 0) {
            int tot = 0;
            for (int w2 = 0; w2 < 16; ++w2) tot += (int)sm.b.wsum[w2];
            cnt[c] = tot;
        }
    }

    // Phase 2a: coarse sums (32 bins per chunk)
    for (int i = t; i < NBINS; i += 1024) atomicAdd(&sm.b.coarse[i >> 5], sm.b.hist[i]);
    __syncthreads();

    // Phase 2b: two-level serial scan from the top (proven logic)
    if (t == 0) {
        unsigned cum = 0; int j = 32;
        for (; j > 0; --j) {
            unsigned h = sm.b.coarse[j];
            if (cum + h >= KSEL) break;
            cum += h;
        }
        int hi = j * 32 + 31; if (hi > NBINS - 1) hi = NBINS - 1;
        int B = 0;
        for (int b = hi; b >= j * 32; --b) {
            unsigned h = sm.b.hist[b];
            if (cum + h >= KSEL) { B = b; break; }
            cum += h;
        }
        sm.b.sB = B; sm.b.sc0 = (int)cum;   // cum = count strictly above bin B
    }
    __syncthreads();
    int B = sm.b.sB, c0 = sm.b.sc0;

    // Phase 3: emit definite winners (LDS); collect boundary candidates
    #pragma unroll
    for (int s = 0; s < 2; ++s) {
        #pragma unroll
        for (int j = 0; j < 4; ++j) {
            unsigned key = keys[s * 4 + j];
            int bin = (key < 0x3E800000u) ? 0 : (int)(1u + ((key - 0x3E800000u) >> 14));
            int i = t * 8 + s * 4 + j;
            if (bin > B) {
                unsigned pos = atomicAdd(&sm.b.above_cnt, 1u);
                sm.b.topk_l[pos] = i;
            } else if (bin == B) {
                unsigned jj = atomicAdd(&sm.b.cand_cnt, 1u);
                if (jj < 2048)
                    sm.b.cand[jj] = ((unsigned long long)key << 32) |
                                    (unsigned long long)(0xFFFFFFFFu - (unsigned)i);
            }
        }
    }
    __syncthreads();

    // Phase 4: wave 0 picks remaining (50 - c0) best boundary candidates
    int m = KSEL - c0;
    int cb = (int)sm.b.cand_cnt; if (cb > 2048) cb = 2048;
    if (t < 64) {
        for (int r = 0; r < m; ++r) {
            unsigned long long best = 0;
            for (int j = t; j < cb; j += 64) {
                unsigned long long v = sm.b.cand[j];
                if (v > best) best = v;
            }
            #pragma unroll
            for (int off = 32; off; off >>= 1) {
                unsigned long long o = __shfl_xor(best, off);
                if (o > best) best = o;
            }
            if (t == 0) sm.b.topk_l[c0 + r] =
                (int)(0xFFFFFFFFu - (unsigned)(best & 0xFFFFFFFFull));
            for (int j = t; j < cb; j += 64)
                if (sm.b.cand[j] == best) sm.b.cand[j] = 0;
        }
    }
    __syncthreads();

    // Phase 5: gather + normalize the 50 winners into nnsel[c*50+row][128].
    {
        int row = t >> 4;
        int ch0 = (t & 15) * 8;
        if (row < KSEL) {
            int px = sm.b.topk_l[row];
            int b = px >> 12, hw = px & (HWSZ - 1);
            const float* src = negative + (size_t)b * CCH * HWSZ + hw;
            float vals[8]; float ss = 0.f;
            #pragma unroll
            for (int k = 0; k < 8; ++k) {
                float v = src[(size_t)(ch0 + k) * HWSZ];
                vals[k] = v; ss += v * v;
            }
            ss += __shfl_xor(ss, 1);
            ss += __shfl_xor(ss, 2);
            ss += __shfl_xor(ss, 4);
            ss += __shfl_xor(ss, 8);
            float inv = 1.0f / fmaxf(sqrtf(ss), 1e-12f);
            float* dst = nnsel + (size_t)(c * KSEL + row) * CCH + ch0;
            #pragma unroll
            for (int k = 0; k < 8; ++k) dst[k] = vals[k] * inv;
        }
    }
}

// ---------------------------------------------------------------------------
// Kernel 2: loss.  Staging verbatim from r4/r6 (coalesced float4).
// Compute restructured to cut LDS reads 40%: thread = (ktid 0..7,
// chh 0..1, pxid 0..15) owns 8 k-rows x 2 pixels x 64 channels; each
// Sl read feeds 4 accumulators (2 px x 2 tensors).  chh halves combine
// via shfl_xor(8) (in-wave), ktid reduce via xor 1/2/4.
// ---------------------------------------------------------------------------
__global__ void __launch_bounds__(256) loss_kernel(
        const float* __restrict__ ni, const float* __restrict__ npos,
        const float* __restrict__ nnsel,
        const int* __restrict__ perm, const int* __restrict__ cnt,
        float* __restrict__ out) {
    __shared__ float Sl[KPAD * SROW];   // 33792 B
    __shared__ float Xl[PXT * SROW];    // 16896 B
    __shared__ float Pl[PXT * SROW];    // 16896 B
    __shared__ float bsum[4];

    int c = blockIdx.y;
    int count = cnt[c];
    int start = blockIdx.x * PXT;
    if (start >= count) return;
    int t = threadIdx.x;

    // stage S: 4 threads per row, 32 ch each (rows 50..63 zeroed)
    {
        int row = t >> 2;
        int ch0 = (t & 3) * 32;
        float* dst = &Sl[row * SROW + ch0];
        if (row < KSEL) {
            const float* src = nnsel + (size_t)(c * KSEL + row) * CCH + ch0;
            #pragma unroll
            for (int i = 0; i < 8; ++i)
                ((float4*)dst)[i] = ((const float4*)src)[i];
        } else {
            float4 z = make_float4(0.f, 0.f, 0.f, 0.f);
            #pragma unroll
            for (int i = 0; i < 8; ++i)
                ((float4*)dst)[i] = z;
        }
    }
    // stage X, P: 8 threads per pixel row, 16 ch each (coalesced float4)
    {
        int row = t >> 3;
        int slot = start + row;
        int px = perm[c * NPIX + ((slot < count) ? slot : start)];
        int ch0 = (t & 7) * 16;
        const float* sx = ni + (size_t)px * CCH + ch0;
        const float* sp = npos + (size_t)px * CCH + ch0;
        float* dx = &Xl[row * SROW + ch0];
        float* dp = &Pl[row * SROW + ch0];
        #pragma unroll
        for (int i = 0; i < 4; ++i) {
            ((float4*)dx)[i] = ((const float4*)sx)[i];
            ((float4*)dp)[i] = ((const float4*)sp)[i];
        }
    }
    __syncthreads();

    int ktid = t & 7, chh = (t >> 3) & 1, pxid = t >> 4;
    float acc_i0[8] = {0.f,0.f,0.f,0.f,0.f,0.f,0.f,0.f};
    float acc_p0[8] = {0.f,0.f,0.f,0.f,0.f,0.f,0.f,0.f};
    float acc_i1[8] = {0.f,0.f,0.f,0.f,0.f,0.f,0.f,0.f};
    float acc_p1[8] = {0.f,0.f,0.f,0.f,0.f,0.f,0.f,0.f};
    float ps0 = 0.f, ps1 = 0.f;
    const float* Xr0 = &Xl[pxid * SROW + chh * 64];
    const float* Pr0 = &Pl[pxid * SROW + chh * 64];
    const float* Xr1 = &Xl[(pxid + 16) * SROW + chh * 64];
    const float* Pr1 = &Pl[(pxid + 16) * SROW + chh * 64];
    const float* Sb  = &Sl[ktid * SROW + chh * 64];

    #pragma unroll 2
    for (int ch = 0; ch < 64; ch += 4) {
        float4 xv0 = *(const float4*)&Xr0[ch];
        float4 pv0 = *(const float4*)&Pr0[ch];
        float4 xv1 = *(const float4*)&Xr1[ch];
        float4 pv1 = *(const float4*)&Pr1[ch];
        ps0 += xv0.x * pv0.x + xv0.y * pv0.y + xv0.z * pv0.z + xv0.w * pv0.w;
        ps1 += xv1.x * pv1.x + xv1.y * pv1.y + xv1.z * pv1.z + xv1.w * pv1.w;
        #pragma unroll
        for (int r = 0; r < 8; ++r) {
            float4 sv = *(const float4*)&Sb[r * 8 * SROW + ch];
            acc_i0[r] += sv.x * xv0.x + sv.y * xv0.y + sv.z * xv0.z + sv.w * xv0.w;
            acc_p0[r] += sv.x * pv0.x + sv.y * pv0.y + sv.z * pv0.z + sv.w * pv0.w;
            acc_i1[r] += sv.x * xv1.x + sv.y * xv1.y + sv.z * xv1.z + sv.w * xv1.w;
            acc_p1[r] += sv.x * pv1.x + sv.y * pv1.y + sv.z * pv1.z + sv.w * pv1.w;
        }
    }

    // combine the two 64-channel halves (partner lane at distance 8)
    #pragma unroll
    for (int r = 0; r < 8; ++r) {
        acc_i0[r] += __shfl_xor(acc_i0[r], 8);
        acc_p0[r] += __shfl_xor(acc_p0[r], 8);
        acc_i1[r] += __shfl_xor(acc_i1[r], 8);
        acc_p1[r] += __shfl_xor(acc_p1[r], 8);
    }
    ps0 += __shfl_xor(ps0, 8);
    ps1 += __shfl_xor(ps1, 8);

    float si0 = 0.f, sp0 = 0.f, si1 = 0.f, sp1 = 0.f;
    #pragma unroll
    for (int r = 0; r < 8; ++r) {
        si0 += expf(acc_i0[r] * TAU_INV);
        sp0 += expf(acc_p0[r] * TAU_INV);
        si1 += expf(acc_i1[r] * TAU_INV);
        sp1 += expf(acc_p1[r] * TAU_INV);
    }
    // reduce over the 8 ktid lanes (xor 1,2,4 stays within the chh octet)
    #pragma unroll
    for (int off = 1; off < 8; off <<= 1) {
        si0 += __shfl_xor(si0, off);
        sp0 += __shfl_xor(sp0, off);
        si1 += __shfl_xor(si1, off);
        sp1 += __shfl_xor(sp1, off);
    }

    float v = 0.f;
    if ((t & 15) == 0) {        // ktid==0 && chh==0 leader per pixel pair
        if (start + pxid < count) {
            float s  = si0 - (float)(KPAD - KSEL);
            float sp = sp0 - (float)(KPAD - KSEL);
            float nom = expf(ps0 * TAU_INV);
            v += -logf(nom / (s + nom + EPSL)) - logf(nom / (sp + nom + EPSL));
        }
        if (start + pxid + 16 < count) {
            float s  = si1 - (float)(KPAD - KSEL);
            float sp = sp1 - (float)(KPAD - KSEL);
            float nom = expf(ps1 * TAU_INV);
            v += -logf(nom / (s + nom + EPSL)) - logf(nom / (sp + nom + EPSL));
        }
        v *= (1.0f / (float)NPIX);
    }
    // sum the 4 pixel-pair leaders in each wave (lanes 0,16,32,48)
    v += __shfl_xor(v, 16);
    v += __shfl_xor(v, 32);
    int w = t >> 6;
    if ((t & 63) == 0) bsum[w] = v;
    __syncthreads();
    if (t == 0) atomicAdd(out, bsum[0] + bsum[1] + bsum[2] + bsum[3]);
}

// ---------------------------------------------------------------------------
extern "C" void kernel_launch(void* const* d_in, const int* in_sizes, int n_in,
                              void* d_out, int out_size, void* d_ws, size_t ws_size,
                              hipStream_t stream) {
    const float* input      = (const float*)d_in[0];
    const float* positive   = (const float*)d_in[1];
    const float* negative   = (const float*)d_in[2];
    const float* in_logits  = (const float*)d_in[3];
    const float* neg_logits = (const float*)d_in[4];
    float* out = (float*)d_out;

    float* ws    = (float*)d_ws;
    float* ni    = ws;                             // [N*C]
    float* np_   = ws + 1048576;                   // [N*C]
    float* nnsel = ws + 2097152;                   // [4*50*128] (pad 32768)
    int*   cnt   = (int*)(ws + 2097152 + 32768);   // [4] (pad 64)
    int*   perm  = cnt + 64;                       // [4*N]

    prep_kernel<<<256 + NCLS, 1024, 0, stream>>>(input, positive, negative,
                                                 in_logits, neg_logits,
                                                 ni, np_, nnsel, perm, cnt, out);
    dim3 lgrid(NPIX / PXT, NCLS);
    loss_kernel<<<lgrid, 256, 0, stream>>>(ni, np_, nnsel, perm, cnt, out);
}

// Round 8
// 104.782 us; speedup vs baseline: 1.0172x; 1.0172x over previous
//
#include <hip/hip_runtime.h>
#include <math.h>

#define TAU_INV (1.0f / 0.07f)
#define KSEL 50
#define KROW 56      // rows per class in LDS (50 real + 6 zero pad -> subtract 6)
#define NPIX 8192
#define CCH 128
#define HWSZ 4096
#define NCLS 4
#define EPSL 1e-8f
#define NBINS 1026
#define PXT 32       // pixels per loss block
#define SROW 132     // LDS row stride in floats
#define SCLS (KROW * SROW + 8)   // per-class stride: +8 floats => class offset 8 banks

// ---------------------------------------------------------------------------
// Kernel 1 (prep, 260 blocks x 1024 threads):
//   blocks 0..3   : per-class top-50 (hist select only — bucketing deleted:
//                   the loss kernel no longer needs perm/cnt), then gather +
//                   normalize the 50 winners into nnsel[c*56+row][128]
//                   (rows 50..55 zeroed).
//   blocks 4..259 : L2-normalize+transpose input/positive (r7 path verbatim).
// ---------------------------------------------------------------------------
__global__ void __launch_bounds__(1024) prep_kernel(
        const float* __restrict__ input, const float* __restrict__ positive,
        const float* __restrict__ negative,
        const float* __restrict__ ilog, const float* __restrict__ nlog,
        float* __restrict__ ni, float* __restrict__ np_,
        float* __restrict__ nnsel,
        float* __restrict__ out) {
    __shared__ union {
        struct {                       // norm+transpose path (~37.6 KB)
            float tile[CCH][65];
            float partial[16][64];
            float invn[64];
        } a;
        struct {                       // topk path (~21 KB)
            unsigned hist[NBINS];
            unsigned coarse[33];
            unsigned long long cand[2048];
            int topk_l[64];
            unsigned above_cnt, cand_cnt;
            int sB, sc0;
        } b;
    } sm;

    int t = threadIdx.x;
    int bid = blockIdx.x;

    if (bid >= NCLS) {
        // ---- norm+transpose: input (blk 0..127), positive (128..255) ----
        int blk = bid - NCLS;
        int tensor = blk >> 7, chunk = blk & 127;
        const float* src = (tensor == 0) ? input : positive;
        float*       dst = (tensor == 0) ? ni    : np_;

        int n0 = chunk * 64;
        int b = n0 >> 12, hw0 = n0 & (HWSZ - 1);
        const float* base = src + (size_t)b * CCH * HWSZ + hw0;

        #pragma unroll
        for (int i = 0; i < 2; ++i) {
            int lin = t + i * 1024;
            int cc = lin >> 4, hwq = (lin & 15) * 4;
            float4 v = *(const float4*)&base[(size_t)cc * HWSZ + hwq];
            sm.a.tile[cc][hwq + 0] = v.x; sm.a.tile[cc][hwq + 1] = v.y;
            sm.a.tile[cc][hwq + 2] = v.z; sm.a.tile[cc][hwq + 3] = v.w;
        }
        __syncthreads();

        {
            int nof = t & 63, part = t >> 6;
            float s = 0.f;
            #pragma unroll
            for (int j = 0; j < 8; ++j) {
                float v = sm.a.tile[part * 8 + j][nof];
                s += v * v;
            }
            sm.a.partial[part][nof] = s;
        }
        __syncthreads();
        if (t < 64) {
            float tot = 0.f;
            #pragma unroll
            for (int p = 0; p < 16; ++p) tot += sm.a.partial[p][t];
            sm.a.invn[t] = 1.0f / fmaxf(sqrtf(tot), 1e-12f);
        }
        __syncthreads();

        #pragma unroll
        for (int i = 0; i < 2; ++i) {
            int lin = t + i * 1024;
            int nf = lin >> 5, cq = (lin & 31) * 4;
            float inv = sm.a.invn[nf];
            float4 o;
            o.x = sm.a.tile[cq + 0][nf] * inv;
            o.y = sm.a.tile[cq + 1][nf] * inv;
            o.z = sm.a.tile[cq + 2][nf] * inv;
            o.w = sm.a.tile[cq + 3][nf] * inv;
            *(float4*)&dst[(size_t)(n0 + nf) * CCH + cq] = o;
        }
        return;
    }

    // ---- topk path: class c (no bucketing — hist select + gather only) ----
    int c = bid;
    if (c == 0 && t == 0) out[0] = 0.0f;

    for (int i = t; i < NBINS; i += 1024) sm.b.hist[i] = 0;
    if (t < 33) sm.b.coarse[t] = 0;
    if (t == 0) { sm.b.above_cnt = 0; sm.b.cand_cnt = 0; }
    __syncthreads();

    // Phase 1: inline softmax/argmax of negative logits -> histogram keys.
    unsigned keys[8];
    #pragma unroll
    for (int s = 0; s < 2; ++s) {
        int i4 = (t * 2 + s) * 4;
        int b = i4 >> 12, hw = i4 & (HWSZ - 1);

        const float* pn = nlog + (size_t)b * NCLS * HWSZ + hw;
        float4 b0 = *(const float4*)&pn[0];
        float4 b1 = *(const float4*)&pn[HWSZ];
        float4 b2 = *(const float4*)&pn[2 * HWSZ];
        float4 b3 = *(const float4*)&pn[3 * HWSZ];

        const float* B0 = (const float*)&b0; const float* B1 = (const float*)&b1;
        const float* B2 = (const float*)&b2; const float* B3 = (const float*)&b3;
        #pragma unroll
        for (int j = 0; j < 4; ++j) {
            float m0 = B0[j], m1 = B1[j], m2 = B2[j], m3 = B3[j];
            int ci = 0; float cv = m0;
            if (m1 > cv) { cv = m1; ci = 1; }
            if (m2 > cv) { cv = m2; ci = 2; }
            if (m3 > cv) { cv = m3; ci = 3; }
            float ssum = expf(m0 - cv) + expf(m1 - cv) + expf(m2 - cv) + expf(m3 - cv);
            float npv = 1.0f / ssum;

            float v = (ci != c) ? npv : 0.0f;
            unsigned key = __float_as_uint(v);
            keys[s * 4 + j] = key;
            int bin = (key < 0x3E800000u) ? 0 : (int)(1u + ((key - 0x3E800000u) >> 14));
            atomicAdd(&sm.b.hist[bin], 1u);
        }
    }
    __syncthreads();

    // Phase 2a: coarse sums (32 bins per chunk)
    for (int i = t; i < NBINS; i += 1024) atomicAdd(&sm.b.coarse[i >> 5], sm.b.hist[i]);
    __syncthreads();

    // Phase 2b: two-level serial scan from the top (proven logic)
    if (t == 0) {
        unsigned cum = 0; int j = 32;
        for (; j > 0; --j) {
            unsigned h = sm.b.coarse[j];
            if (cum + h >= KSEL) break;
            cum += h;
        }
        int hi = j * 32 + 31; if (hi > NBINS - 1) hi = NBINS - 1;
        int B = 0;
        for (int b = hi; b >= j * 32; --b) {
            unsigned h = sm.b.hist[b];
            if (cum + h >= KSEL) { B = b; break; }
            cum += h;
        }
        sm.b.sB = B; sm.b.sc0 = (int)cum;   // cum = count strictly above bin B
    }
    __syncthreads();
    int B = sm.b.sB, c0 = sm.b.sc0;

    // Phase 3: emit definite winners (LDS); collect boundary candidates
    #pragma unroll
    for (int s = 0; s < 2; ++s) {
        #pragma unroll
        for (int j = 0; j < 4; ++j) {
            unsigned key = keys[s * 4 + j];
            int bin = (key < 0x3E800000u) ? 0 : (int)(1u + ((key - 0x3E800000u) >> 14));
            int i = t * 8 + s * 4 + j;
            if (bin > B) {
                unsigned pos = atomicAdd(&sm.b.above_cnt, 1u);
                sm.b.topk_l[pos] = i;
            } else if (bin == B) {
                unsigned jj = atomicAdd(&sm.b.cand_cnt, 1u);
                if (jj < 2048)
                    sm.b.cand[jj] = ((unsigned long long)key << 32) |
                                    (unsigned long long)(0xFFFFFFFFu - (unsigned)i);
            }
        }
    }
    __syncthreads();

    // Phase 4: wave 0 picks remaining (50 - c0) best boundary candidates
    int m = KSEL - c0;
    int cb = (int)sm.b.cand_cnt; if (cb > 2048) cb = 2048;
    if (t < 64) {
        for (int r = 0; r < m; ++r) {
            unsigned long long best = 0;
            for (int j = t; j < cb; j += 64) {
                unsigned long long v = sm.b.cand[j];
                if (v > best) best = v;
            }
            #pragma unroll
            for (int off = 32; off; off >>= 1) {
                unsigned long long o = __shfl_xor(best, off);
                if (o > best) best = o;
            }
            if (t == 0) sm.b.topk_l[c0 + r] =
                (int)(0xFFFFFFFFu - (unsigned)(best & 0xFFFFFFFFull));
            for (int j = t; j < cb; j += 64)
                if (sm.b.cand[j] == best) sm.b.cand[j] = 0;
        }
    }
    __syncthreads();

    // Phase 5: gather + normalize winners into nnsel[c*KROW+row][128];
    // rows 50..55 written as zeros (pad -> loss subtracts exp(0)*6).
    {
        int row = t >> 4;
        int ch0 = (t & 15) * 8;
        if (row < KSEL) {
            int px = sm.b.topk_l[row];
            int b = px >> 12, hw = px & (HWSZ - 1);
            const float* src = negative + (size_t)b * CCH * HWSZ + hw;
            float vals[8]; float ss = 0.f;
            #pragma unroll
            for (int k = 0; k < 8; ++k) {
                float v = src[(size_t)(ch0 + k) * HWSZ];
                vals[k] = v; ss += v * v;
            }
            ss += __shfl_xor(ss, 1);
            ss += __shfl_xor(ss, 2);
            ss += __shfl_xor(ss, 4);
            ss += __shfl_xor(ss, 8);
            float inv = 1.0f / fmaxf(sqrtf(ss), 1e-12f);
            float* dst = nnsel + (size_t)(c * KROW + row) * CCH + ch0;
            #pragma unroll
            for (int k = 0; k < 8; ++k) dst[k] = vals[k] * inv;
        } else if (row < KROW) {
            float* dst = nnsel + (size_t)(c * KROW + row) * CCH + ch0;
            #pragma unroll
            for (int k = 0; k < 8; ++k) dst[k] = 0.f;
        }
    }
}

// ---------------------------------------------------------------------------
// Kernel 2: loss.  Block = 32 CONSECUTIVE pixels (no perm indirection).
// All four class S-tiles live in LDS (4 x 56 rows, ~152 KB total block LDS);
// each pixel's class is computed inline from ilog (argmax).  Thread
// (ktid 0..7, pxid 0..31) owns 7 k-rows x 1 pixel of its pixel's class tile.
// X/P staging is perfectly sequential float4 from ni/np_.
// ---------------------------------------------------------------------------
__global__ void __launch_bounds__(256) loss_kernel(
        const float* __restrict__ ni, const float* __restrict__ npos,
        const float* __restrict__ nnsel, const float* __restrict__ ilog,
        float* __restrict__ out) {
    __shared__ float Sl[NCLS * SCLS];   // 118,400 B (class stride: 8-bank offset)
    __shared__ float Xl[PXT * SROW];    // 16,896 B
    __shared__ float Pl[PXT * SROW];    // 16,896 B
    __shared__ int   clsL[PXT];
    __shared__ float bsum[4];

    int t = threadIdx.x;
    int start = blockIdx.x * PXT;

    // stage S: all 4 class tiles, straight copy (pad rows already zero)
    for (int i = t; i < NCLS * KROW * 32; i += 256) {
        int rowq = i >> 5;                  // 0..223
        int q = i & 31;
        int cc = rowq / KROW;
        int rr = rowq - cc * KROW;
        float4 v = *(const float4*)&nnsel[(size_t)rowq * CCH + q * 4];
        *(float4*)&Sl[cc * SCLS + rr * SROW + q * 4] = v;
    }
    // per-pixel class from input logits (argmax, first-max-wins)
    if (t < PXT) {
        int px = start + t;
        int b = px >> 12, hw = px & (HWSZ - 1);
        const float* pi = ilog + (size_t)b * NCLS * HWSZ + hw;
        float l0 = pi[0], l1 = pi[HWSZ], l2 = pi[2 * HWSZ], l3 = pi[3 * HWSZ];
        int bi = 0; float bv = l0;
        if (l1 > bv) { bv = l1; bi = 1; }
        if (l2 > bv) { bv = l2; bi = 2; }
        if (l3 > bv) { bv = l3; bi = 3; }
        clsL[t] = bi;
    }
    // stage X, P: 8 threads per pixel row, 16 ch each — fully sequential
    {
        int row = t >> 3;
        int px = start + row;
        int ch0 = (t & 7) * 16;
        const float* sx = ni + (size_t)px * CCH + ch0;
        const float* sp = npos + (size_t)px * CCH + ch0;
        float* dx = &Xl[row * SROW + ch0];
        float* dp = &Pl[row * SROW + ch0];
        #pragma unroll
        for (int i = 0; i < 4; ++i) {
            ((float4*)dx)[i] = ((const float4*)sx)[i];
            ((float4*)dp)[i] = ((const float4*)sp)[i];
        }
    }
    __syncthreads();

    int ktid = t & 7, pxid = t >> 3;
    int cls = clsL[pxid];
    const float* Sb = &Sl[cls * SCLS + ktid * SROW];
    const float* Xr = &Xl[pxid * SROW];
    const float* Pr = &Pl[pxid * SROW];

    float acc_i[7] = {0.f, 0.f, 0.f, 0.f, 0.f, 0.f, 0.f};
    float acc_p[7] = {0.f, 0.f, 0.f, 0.f, 0.f, 0.f, 0.f};
    float ps = 0.f;

    #pragma unroll 2
    for (int ch = 0; ch < CCH; ch += 4) {
        float4 xv = *(const float4*)&Xr[ch];
        float4 pv = *(const float4*)&Pr[ch];
        ps += xv.x * pv.x + xv.y * pv.y + xv.z * pv.z + xv.w * pv.w;
        #pragma unroll
        for (int r = 0; r < 7; ++r) {
            float4 sv = *(const float4*)&Sb[r * 8 * SROW + ch];
            acc_i[r] += sv.x * xv.x + sv.y * xv.y + sv.z * xv.z + sv.w * xv.w;
            acc_p[r] += sv.x * pv.x + sv.y * pv.y + sv.z * pv.z + sv.w * pv.w;
        }
    }

    float si = 0.f, spp = 0.f;
    #pragma unroll
    for (int r = 0; r < 7; ++r) {
        si  += expf(acc_i[r] * TAU_INV);
        spp += expf(acc_p[r] * TAU_INV);
    }
    // reduce over the 8 ktid lanes (consecutive within the wave)
    #pragma unroll
    for (int off = 1; off < 8; off <<= 1) {
        si  += __shfl_xor(si, off);
        spp += __shfl_xor(spp, off);
    }

    float v = 0.f;
    if (ktid == 0) {
        si  -= (float)(KROW - KSEL);   // remove exp(0)=1 of the 6 zero rows
        spp -= (float)(KROW - KSEL);
        float nom = expf(ps * TAU_INV);
        float li = -logf(nom / (si + nom + EPSL));
        float lp = -logf(nom / (spp + nom + EPSL));
        v = (li + lp) * (1.0f / (float)NPIX);
    }
    // sum the 8 per-pixel leaders in each wave, then block, then global
    v += __shfl_xor(v, 8);
    v += __shfl_xor(v, 16);
    v += __shfl_xor(v, 32);
    int w = t >> 6;
    if ((t & 63) == 0) bsum[w] = v;
    __syncthreads();
    if (t == 0) atomicAdd(out, bsum[0] + bsum[1] + bsum[2] + bsum[3]);
}

// ---------------------------------------------------------------------------
extern "C" void kernel_launch(void* const* d_in, const int* in_sizes, int n_in,
                              void* d_out, int out_size, void* d_ws, size_t ws_size,
                              hipStream_t stream) {
    const float* input      = (const float*)d_in[0];
    const float* positive   = (const float*)d_in[1];
    const float* negative   = (const float*)d_in[2];
    const float* in_logits  = (const float*)d_in[3];
    const float* neg_logits = (const float*)d_in[4];
    float* out = (float*)d_out;

    float* ws    = (float*)d_ws;
    float* ni    = ws;                             // [N*C]
    float* np_   = ws + 1048576;                   // [N*C]
    float* nnsel = ws + 2097152;                   // [4*56*128] (pad 32768)

    prep_kernel<<<256 + NCLS, 1024, 0, stream>>>(input, positive, negative,
                                                 in_logits, neg_logits,
                                                 ni, np_, nnsel, out);
    loss_kernel<<<NPIX / PXT, 256, 0, stream>>>(ni, np_, nnsel, in_logits, out);
}

// Round 9
// 98.060 us; speedup vs baseline: 1.0869x; 1.0685x over previous
//
#include <hip/hip_runtime.h>
#include <math.h>

#define TAU_INV (1.0f / 0.07f)
#define KSEL 50
#define KPAD 64      // zero-padded rows 50..63: dot=0 -> exp=1 -> subtract 14
#define NPIX 8192
#define CCH 128
#define HWSZ 4096
#define NCLS 4
#define EPSL 1e-8f
#define NBINS 1026
#define PXT 32       // pixels per loss block
#define SROW 132     // LDS row stride in floats

// ---------------------------------------------------------------------------
// Kernel 1 (mega): blocks 0..383 = L2-normalize+transpose the 3 tensors
// (float4 global traffic both directions); blocks 384..391 = seg path,
// 4 pixels/thread via float4.
// ---------------------------------------------------------------------------
__global__ void __launch_bounds__(256) mega_kernel(
        const float* __restrict__ input, const float* __restrict__ positive,
        const float* __restrict__ negative,
        const float* __restrict__ ilog, const float* __restrict__ nlog,
        float* __restrict__ ni, float* __restrict__ np_, float* __restrict__ nn,
        int* __restrict__ seg_in, int* __restrict__ seg_neg,
        float* __restrict__ neg_prob) {
    __shared__ float tile[CCH][65];   // stride 65: conflict-free col/row mix
    __shared__ float partial[4][64];
    __shared__ float invn[64];

    int t = threadIdx.x;
    int blk = blockIdx.x;

    if (blk < 384) {
        // ---- norm+transpose path ----
        int tensor = blk >> 7, chunk = blk & 127;
        const float* src = (tensor == 0) ? input : (tensor == 1) ? positive : negative;
        float*       dst = (tensor == 0) ? ni    : (tensor == 1) ? np_      : nn;

        int n0 = chunk * 64;
        int b = n0 >> 12, hw0 = n0 & (HWSZ - 1);
        const float* base = src + (size_t)b * CCH * HWSZ + hw0;

        // load: float4 along hw; 4 scalar LDS writes (conflict-free, stride 65)
        #pragma unroll
        for (int i = 0; i < 8; ++i) {
            int lin = t + i * 256;
            int c = lin >> 4, hwq = (lin & 15) * 4;
            float4 v = *(const float4*)&base[(size_t)c * HWSZ + hwq];
            tile[c][hwq + 0] = v.x; tile[c][hwq + 1] = v.y;
            tile[c][hwq + 2] = v.z; tile[c][hwq + 3] = v.w;
        }
        __syncthreads();

        int nof = t & 63, part = t >> 6;
        float s = 0.f;
        #pragma unroll
        for (int j = 0; j < 32; ++j) {
            float v = tile[part * 32 + j][nof];
            s += v * v;
        }
        partial[part][nof] = s;
        __syncthreads();
        if (t < 64) {
            float tot = partial[0][t] + partial[1][t] + partial[2][t] + partial[3][t];
            invn[t] = 1.0f / fmaxf(sqrtf(tot), 1e-12f);
        }
        __syncthreads();

        // store: gather 4 consecutive channels (4-way LDS conflict, cheap) ->
        // one float4 coalesced global store
        #pragma unroll
        for (int i = 0; i < 8; ++i) {
            int lin = t + i * 256;
            int nf = lin >> 5, cq = (lin & 31) * 4;
            float inv = invn[nf];
            float4 o;
            o.x = tile[cq + 0][nf] * inv;
            o.y = tile[cq + 1][nf] * inv;
            o.z = tile[cq + 2][nf] * inv;
            o.w = tile[cq + 3][nf] * inv;
            *(float4*)&dst[(size_t)(n0 + nf) * CCH + cq] = o;
        }
    } else {
        // ---- seg path: 4 consecutive pixels per thread ----
        int n0 = ((blk - 384) * 256 + t) * 4;
        int b = n0 >> 12, hw = n0 & (HWSZ - 1);

        const float* pi = ilog + (size_t)b * NCLS * HWSZ + hw;
        float4 a0 = *(const float4*)&pi[0];
        float4 a1 = *(const float4*)&pi[HWSZ];
        float4 a2 = *(const float4*)&pi[2 * HWSZ];
        float4 a3 = *(const float4*)&pi[3 * HWSZ];
        const float* pn = nlog + (size_t)b * NCLS * HWSZ + hw;
        float4 b0 = *(const float4*)&pn[0];
        float4 b1 = *(const float4*)&pn[HWSZ];
        float4 b2 = *(const float4*)&pn[2 * HWSZ];
        float4 b3 = *(const float4*)&pn[3 * HWSZ];

        int4 si4, sn4; float4 npb;
        const float* A0 = (const float*)&a0; const float* A1 = (const float*)&a1;
        const float* A2 = (const float*)&a2; const float* A3 = (const float*)&a3;
        const float* B0 = (const float*)&b0; const float* B1 = (const float*)&b1;
        const float* B2 = (const float*)&b2; const float* B3 = (const float*)&b3;
        int* SI = (int*)&si4; int* SN = (int*)&sn4; float* NP = (float*)&npb;
        #pragma unroll
        for (int j = 0; j < 4; ++j) {
            float l0 = A0[j], l1 = A1[j], l2 = A2[j], l3 = A3[j];
            int bi = 0; float bv = l0;
            if (l1 > bv) { bv = l1; bi = 1; }
            if (l2 > bv) { bv = l2; bi = 2; }
            if (l3 > bv) { bv = l3; bi = 3; }
            SI[j] = bi;
            float m0 = B0[j], m1 = B1[j], m2 = B2[j], m3 = B3[j];
            int ci = 0; float cv = m0;
            if (m1 > cv) { cv = m1; ci = 1; }
            if (m2 > cv) { cv = m2; ci = 2; }
            if (m3 > cv) { cv = m3; ci = 3; }
            SN[j] = ci;
            float s = expf(m0 - cv) + expf(m1 - cv) + expf(m2 - cv) + expf(m3 - cv);
            NP[j] = 1.0f / s;
        }
        *(int4*)&seg_in[n0] = si4;
        *(int4*)&seg_neg[n0] = sn4;
        *(float4*)&neg_prob[n0] = npb;
    }
}

// ---------------------------------------------------------------------------
// Kernel 2: per class c (one block each): top-50 histogram select +
// same-class pixel bucketing + out zeroing.  Vectorized phase-1 loads.
// ---------------------------------------------------------------------------
__global__ void __launch_bounds__(1024) topk_kernel(
        const int* __restrict__ seg_in, const int* __restrict__ seg_neg,
        const float* __restrict__ neg_prob,
        int* __restrict__ topk, int* __restrict__ perm, int* __restrict__ cnt,
        float* __restrict__ out) {
    __shared__ unsigned hist[NBINS];
    __shared__ unsigned coarse[33];
    __shared__ unsigned long long cand[2048];
    __shared__ unsigned above_cnt, cand_cnt, bucket_cnt;
    __shared__ int sB, sc0;

    int c = blockIdx.x, t = threadIdx.x;
    if (c == 0 && t == 0) out[0] = 0.0f;

    for (int i = t; i < NBINS; i += 1024) hist[i] = 0;
    if (t < 33) coarse[t] = 0;
    if (t == 0) { above_cnt = 0; cand_cnt = 0; bucket_cnt = 0; }
    __syncthreads();

    // Phase 1: histogram + same-class pixel bucketing (int4/float4 loads)
    unsigned keys[8]; int bins[8];
    #pragma unroll
    for (int s = 0; s < 2; ++s) {
        int i4 = (t + s * 1024) * 4;
        int4 sn = *(const int4*)&seg_neg[i4];
        int4 sg = *(const int4*)&seg_in[i4];
        float4 npv = *(const float4*)&neg_prob[i4];
        const int* SN = (const int*)&sn;
        const int* SG = (const int*)&sg;
        const float* NP = (const float*)&npv;
        #pragma unroll
        for (int j = 0; j < 4; ++j) {
            float v = (SN[j] != c) ? NP[j] : 0.0f;
            unsigned key = __float_as_uint(v);
            int bin = (key < 0x3E800000u) ? 0 : (int)(1u + ((key - 0x3E800000u) >> 14));
            keys[s * 4 + j] = key; bins[s * 4 + j] = bin;
            atomicAdd(&hist[bin], 1u);
            if (SG[j] == c) {
                unsigned p = atomicAdd(&bucket_cnt, 1u);
                perm[c * NPIX + p] = i4 + j;   // order within class is free
            }
        }
    }
    __syncthreads();
    if (t == 0) cnt[c] = (int)bucket_cnt;

    // Phase 2a: coarse sums (32 bins per chunk)
    for (int i = t; i < NBINS; i += 1024) atomicAdd(&coarse[i >> 5], hist[i]);
    __syncthreads();

    // Phase 2b: two-level serial scan from the top (<= 33+32 steps)
    if (t == 0) {
        unsigned cum = 0; int j = 32;
        for (; j > 0; --j) {
            unsigned h = coarse[j];
            if (cum + h >= KSEL) break;
            cum += h;
        }
        int hi = j * 32 + 31; if (hi > NBINS - 1) hi = NBINS - 1;
        int B = 0;
        for (int b = hi; b >= j * 32; --b) {
            unsigned h = hist[b];
            if (cum + h >= KSEL) { B = b; break; }
            cum += h;
        }
        sB = B; sc0 = (int)cum;   // cum = count strictly above bin B (< 50)
    }
    __syncthreads();
    int B = sB, c0 = sc0;

    // Phase 3: emit definite winners; collect boundary-bin candidates
    #pragma unroll
    for (int s = 0; s < 8; ++s) {
        int i = (t + (s >> 2) * 1024) * 4 + (s & 3);
        if (bins[s] > B) {
            unsigned pos = atomicAdd(&above_cnt, 1u);
            topk[c * KSEL + pos] = i;
        } else if (bins[s] == B) {
            unsigned j = atomicAdd(&cand_cnt, 1u);
            if (j < 2048)
                cand[j] = ((unsigned long long)keys[s] << 32) |
                          (unsigned long long)(0xFFFFFFFFu - (unsigned)i);
        }
    }
    __syncthreads();

    // Phase 4: wave 0 picks remaining (50 - c0) best boundary candidates.
    int m = KSEL - c0;
    int cb = (int)cand_cnt; if (cb > 2048) cb = 2048;
    if (t < 64) {
        for (int r = 0; r < m; ++r) {
            unsigned long long best = 0;
            for (int j = t; j < cb; j += 64) {
                unsigned long long v = cand[j];
                if (v > best) best = v;
            }
            #pragma unroll
            for (int off = 32; off; off >>= 1) {
                unsigned long long o = __shfl_xor(best, off);
                if (o > best) best = o;
            }
            if (t == 0) topk[c * KSEL + c0 + r] = (int)(0xFFFFFFFFu - (unsigned)(best & 0xFFFFFFFFull));
            for (int j = t; j < cb; j += 64)
                if (cand[j] == best) cand[j] = 0;
        }
    }
}

// ---------------------------------------------------------------------------
// Kernel 3: same-class GEMM-style loss.  Block = 32 pixels of one class.
// Thread (ktid 0..7, pxid 0..31) owns 8 k-rows x 1 pixel; dots accumulate in
// registers over all 128 channels (no shuffles in inner loop).
// Accumulates (li+lp)/NPIX straight into d_out (zeroed by topk_kernel).
// ---------------------------------------------------------------------------
__global__ void __launch_bounds__(256) loss_kernel(
        const float* __restrict__ ni, const float* __restrict__ npos,
        const float* __restrict__ nn, const int* __restrict__ topk,
        const int* __restrict__ perm, const int* __restrict__ cnt,
        float* __restrict__ out) {
    __shared__ float Sl[KPAD * SROW];   // 33792 B
    __shared__ float Xl[PXT * SROW];    // 16896 B
    __shared__ float Pl[PXT * SROW];    // 16896 B
    __shared__ float bsum[4];

    int c = blockIdx.y;
    int count = cnt[c];
    int start = blockIdx.x * PXT;
    if (start >= count) return;
    int t = threadIdx.x;

    // stage S: 4 threads per row, 32 ch each
    {
        int row = t >> 2;
        int ch0 = (t & 3) * 32;
        float* dst = &Sl[row * SROW + ch0];
        if (row < KSEL) {
            const float* src = nn + (size_t)topk[c * KSEL + row] * CCH + ch0;
            #pragma unroll
            for (int i = 0; i < 8; ++i)
                ((float4*)dst)[i] = ((const float4*)src)[i];
        } else {
            float4 z = make_float4(0.f, 0.f, 0.f, 0.f);
            #pragma unroll
            for (int i = 0; i < 8; ++i)
                ((float4*)dst)[i] = z;
        }
    }
    // stage X, P: 8 threads per pixel row, 16 ch each
    {
        int row = t >> 3;
        int slot = start + row;
        int px = perm[c * NPIX + ((slot < count) ? slot : start)];
        int ch0 = (t & 7) * 16;
        const float* sx = ni + (size_t)px * CCH + ch0;
        const float* sp = npos + (size_t)px * CCH + ch0;
        float* dx = &Xl[row * SROW + ch0];
        float* dp = &Pl[row * SROW + ch0];
        #pragma unroll
        for (int i = 0; i < 4; ++i) {
            ((float4*)dx)[i] = ((const float4*)sx)[i];
            ((float4*)dp)[i] = ((const float4*)sp)[i];
        }
    }
    __syncthreads();

    int ktid = t & 7, pxid = t >> 3;
    float acc_i[8] = {0.f, 0.f, 0.f, 0.f, 0.f, 0.f, 0.f, 0.f};
    float acc_p[8] = {0.f, 0.f, 0.f, 0.f, 0.f, 0.f, 0.f, 0.f};
    float ps = 0.f;
    const float* Xr = &Xl[pxid * SROW];
    const float* Pr = &Pl[pxid * SROW];

    #pragma unroll 2
    for (int ch = 0; ch < CCH; ch += 4) {
        float4 xv = *(const float4*)&Xr[ch];
        float4 pv = *(const float4*)&Pr[ch];
        ps += xv.x * pv.x + xv.y * pv.y + xv.z * pv.z + xv.w * pv.w;
        #pragma unroll
        for (int r = 0; r < 8; ++r) {
            float4 sv = *(const float4*)&Sl[(ktid + r * 8) * SROW + ch];
            acc_i[r] += sv.x * xv.x + sv.y * xv.y + sv.z * xv.z + sv.w * xv.w;
            acc_p[r] += sv.x * pv.x + sv.y * pv.y + sv.z * pv.z + sv.w * pv.w;
        }
    }

    float si = 0.f, spp = 0.f;
    #pragma unroll
    for (int r = 0; r < 8; ++r) {
        si  += expf(acc_i[r] * TAU_INV);
        spp += expf(acc_p[r] * TAU_INV);
    }
    // reduce over the 8 ktid lanes (consecutive within the wave)
    #pragma unroll
    for (int off = 1; off < 8; off <<= 1) {
        si  += __shfl_xor(si, off);
        spp += __shfl_xor(spp, off);
    }

    float v = 0.f;
    if (ktid == 0 && (start + pxid) < count) {
        si  -= (float)(KPAD - KSEL);   // remove exp(0)=1 of the 14 zero rows
        spp -= (float)(KPAD - KSEL);
        float nom = expf(ps * TAU_INV);
        float li = -logf(nom / (si + nom + EPSL));
        float lp = -logf(nom / (spp + nom + EPSL));
        v = (li + lp) * (1.0f / (float)NPIX);
    }
    // sum the 8 per-pixel leaders in each wave, then block, then global
    v += __shfl_xor(v, 8);
    v += __shfl_xor(v, 16);
    v += __shfl_xor(v, 32);
    int w = t >> 6;
    if ((t & 63) == 0) bsum[w] = v;
    __syncthreads();
    if (t == 0) atomicAdd(out, bsum[0] + bsum[1] + bsum[2] + bsum[3]);
}

// ---------------------------------------------------------------------------
extern "C" void kernel_launch(void* const* d_in, const int* in_sizes, int n_in,
                              void* d_out, int out_size, void* d_ws, size_t ws_size,
                              hipStream_t stream) {
    const float* input      = (const float*)d_in[0];
    const float* positive   = (const float*)d_in[1];
    const float* negative   = (const float*)d_in[2];
    const float* in_logits  = (const float*)d_in[3];
    const float* neg_logits = (const float*)d_in[4];
    float* out = (float*)d_out;

    float* ws  = (float*)d_ws;
    float* ni  = ws;                               // [N*C]
    float* np_ = ws + 1048576;                     // [N*C]
    float* nn  = ws + 2097152;                     // [N*C]
    int*   seg_in   = (int*)(ws + 3145728);        // [N]
    int*   seg_neg  = seg_in + NPIX;               // [N]
    float* neg_prob = (float*)(seg_neg + NPIX);    // [N]
    int*   topk     = (int*)(neg_prob + NPIX);     // [4*50] (pad 256)
    int*   cnt      = topk + 256;                  // [4] (pad 64)
    int*   perm     = cnt + 64;                    // [4*N]

    mega_kernel<<<392, 256, 0, stream>>>(input, positive, negative,
                                         in_logits, neg_logits,
                                         ni, np_, nn, seg_in, seg_neg, neg_prob);
    topk_kernel<<<NCLS, 1024, 0, stream>>>(seg_in, seg_neg, neg_prob,
                                           topk, perm, cnt, out);
    dim3 lgrid(NPIX / PXT, NCLS);
    loss_kernel<<<lgrid, 256, 0, stream>>>(ni, np_, nn, topk, perm, cnt, out);
}